// Round 10
// baseline (2611.886 us; speedup 1.0000x reference)
//
#include <hip/hip_runtime.h>
#include <math.h>
#include <stdint.h>

namespace {

constexpr int NROW = 16384;   // B*A
constexpr int NF   = 512;     // n_in
constexpr int MIND = 2048;    // inducing points
constexpr float CC = 0.98f;   // centering constant: Kx = exp(-d), d ~ 0.004

typedef _Float16 half8 __attribute__((ext_vector_type(8)));
typedef _Float16 half4v __attribute__((ext_vector_type(4)));
typedef float floatx4 __attribute__((ext_vector_type(4)));

__device__ __forceinline__ void gload16(const void* g, void* l) {
  __builtin_amdgcn_global_load_lds(
      (__attribute__((address_space(1))) void*)g,
      (__attribute__((address_space(3))) void*)l, 16, 0, 0);
}

#define MEMFENCE asm volatile("" ::: "memory")
#define GATE(N) asm volatile("s_waitcnt vmcnt(" #N ")" ::: "memory")

// ---------------------------------------------------------------- stats ----
__global__ __launch_bounds__(256) void stats_kernel(
    const float* __restrict__ x, const int* __restrict__ mask,
    float* __restrict__ sum, float* __restrict__ sumsq, float* __restrict__ cnt)
{
  const int t = threadIdx.x;
  const int row0 = blockIdx.x * 64;
  float s0 = 0.f, s1 = 0.f, q0 = 0.f, q1 = 0.f, c = 0.f;
  for (int r = 0; r < 64; ++r) {
    const int row = row0 + r;
    const float m = (mask[row] != 0) ? 1.f : 0.f;
    const float v0 = x[(size_t)row * NF + t];
    const float v1 = x[(size_t)row * NF + t + 256];
    s0 += m * v0; q0 += m * v0 * v0;
    s1 += m * v1; q1 += m * v1 * v1;
    c += m;
  }
  atomicAdd(&sum[t], s0);        atomicAdd(&sum[t + 256], s1);
  atomicAdd(&sumsq[t], q0);      atomicAdd(&sumsq[t + 256], q1);
  if (t == 0) atomicAdd(cnt, c);
}

// z rows (masked, normalized, /g2) fp16 + zi rows fp16 + fp32 norms of the
// fp16-ROUNDED values.  FOLDED IN (R10): per-thread finalize_stats (each
// thread derives mean/zs/gi for its own 2 columns; block 0 persists
// meanv/stdv for PASS1) and ip^T fp16 transpose (256 extra blocks).
__global__ __launch_bounds__(256) void make_z(
    const float* __restrict__ x, const int* __restrict__ mask,
    const float* __restrict__ ip, const float* __restrict__ sum,
    const float* __restrict__ sumsq, const float* __restrict__ cnt,
    const float* __restrict__ gamma,
    _Float16* __restrict__ Zh, _Float16* __restrict__ Zih,
    float* __restrict__ rnorm, float* __restrict__ cnorm,
    float* __restrict__ meanv, float* __restrict__ stdv,
    _Float16* __restrict__ ipTh)
{
  __shared__ float T[64][65];
  const int row = blockIdx.x;
  const int t = threadIdx.x;

  if (row >= NROW + MIND) {            // ---- ipTh tile (256 blocks) ----
    const int idx2 = row - (NROW + MIND);
    const int j0 = (idx2 & 31) * 64, f0 = (idx2 >> 5) * 64;
    #pragma unroll
    for (int l = 0; l < 16; ++l) {
      const int idx = t + l * 256;
      T[idx >> 6][idx & 63] = ip[(size_t)(j0 + (idx >> 6)) * NF + f0 + (idx & 63)];
    }
    __syncthreads();
    #pragma unroll
    for (int l = 0; l < 16; ++l) {
      const int idx = t + l * 256;
      const int fr = idx >> 6, jc = idx & 63;
      ipTh[(size_t)(f0 + fr) * MIND + j0 + jc] = (_Float16)T[jc][fr];
    }
    return;
  }

  // per-thread finalize for cols t and t+256
  const float n = cnt[0];
  float mu[2], zs[2], gi[2];
  #pragma unroll
  for (int h = 0; h < 2; ++h) {
    const int f = t + h * 256;
    const float m0 = sum[f] / n;
    const float var = (sumsq[f] - sum[f] * m0) / (n - 1.0f);
    const float sd = sqrtf(var) + 1e-5f;
    const float g = gamma[f];
    const float g2 = g * g + 0.001f;
    mu[h] = m0; zs[h] = 1.0f / (sd * g2); gi[h] = 1.0f / g2;
    if (row == 0) { meanv[f] = m0; stdv[f] = sd; }
  }

  float v0, v1;
  if (row < NROW) {
    const float m = (mask[row] != 0) ? 1.f : 0.f;
    v0 = (x[(size_t)row * NF + t      ] - mu[0]) * zs[0] * m;
    v1 = (x[(size_t)row * NF + t + 256] - mu[1]) * zs[1] * m;
    const _Float16 h0 = (_Float16)v0, h1 = (_Float16)v1;
    Zh[(size_t)row * NF + t] = h0;
    Zh[(size_t)row * NF + t + 256] = h1;
    v0 = (float)h0; v1 = (float)h1;
  } else {
    const int r = row - NROW;
    v0 = ip[(size_t)r * NF + t      ] * gi[0];
    v1 = ip[(size_t)r * NF + t + 256] * gi[1];
    const _Float16 h0 = (_Float16)v0, h1 = (_Float16)v1;
    Zih[(size_t)r * NF + t] = h0;
    Zih[(size_t)r * NF + t + 256] = h1;
    v0 = (float)h0; v1 = (float)h1;
  }
  float nrm = v0 * v0 + v1 * v1;
  #pragma unroll
  for (int off = 32; off; off >>= 1) nrm += __shfl_xor(nrm, off);
  if ((t & 63) == 0) T[0][t >> 6] = nrm;
  __syncthreads();
  if (t == 0) {
    const float s = T[0][0] + T[0][1] + T[0][2] + T[0][3];
    if (row < NROW) rnorm[row] = s; else cnorm[row - NROW] = s;
  }
}

// ------------------------------------------------- 256x256 deep-pipe GEMM --
// (R5 proven structure: fused-by-concatenation, XCD swizzle, LDS slot
// swizzle, counted vmcnt(8) 4-buffer pipeline.)
// PASS 0: A' = [Zh;Zih], B = Zih, grid (8,72): DK (bm<64) + Kreg (bm>=64)
// PASS 1: A = DK, B' = [Kih;Rt], grid (10,64): varacc (bn<8) + x_new
// PASS 2: A = ipTh, B = Kih, grid (8,6): wgid<16 -> Rt = fp16(ip^T Kinv)
//         (Kinv symmetry); wgid>=16 (32 blocks) -> colsumR = ip^T u (fused)
template <int PASS>
__global__ __launch_bounds__(512, 2) void mfma_gemm256f(
    const _Float16* __restrict__ A, const _Float16* __restrict__ B, int K,
    const float* __restrict__ rn, const float* __restrict__ cn,
    _Float16* __restrict__ DKout, float* __restrict__ Cf,
    const _Float16* __restrict__ DK, const float* __restrict__ u,
    float* __restrict__ varacc,
    const float* __restrict__ colsumR, const float* __restrict__ stdv,
    const float* __restrict__ meanv, const int* __restrict__ mask)
{
  __shared__ __align__(16) _Float16 Asmem[4][256 * 32];
  __shared__ __align__(16) _Float16 Bsmem[4][256 * 32];

  const int tid = threadIdx.x;
  const int w = tid >> 6, L = tid & 63;
  const int wm = w >> 2, wn = w & 3;          // 2 x 4 waves
  const int lq = L >> 4, lr = L & 15;
  // ---- XCD-aware remap (T1): same-bm blocks contiguous on one XCD ----
  int bn, bm;
  if constexpr (PASS == 0) {
    const int wgid = blockIdx.y * 8 + blockIdx.x;    // grid (8,72)
    const int xcd = wgid & 7, q = wgid >> 3;         // q: 0..71
    bm = xcd + 8 * (q >> 3);                         // 0..71, bijective
    bn = q & 7;                                      // 0..7
  } else if constexpr (PASS == 1) {
    const int wgid = blockIdx.y * 10 + blockIdx.x;   // grid (10,64)
    const int xcd = wgid & 7, q = wgid >> 3;         // q: 0..79
    bm = xcd + 8 * (q / 10);                         // 0..63, bijective
    bn = q % 10;                                     // 0..9
  } else {
    const int wgid = blockIdx.y * 8 + blockIdx.x;    // grid (8,6) = 48
    if (wgid >= 16) {                                // fused colsum_u
      const int r0 = (wgid - 16) * 64;
      float s = 0.f;
      for (int r = 0; r < 64; ++r)
        s += u[r0 + r] * rn[(size_t)(r0 + r) * NF + tid];  // rn carries ip
      atomicAdd(&varacc[tid], s);                    // varacc carries colsumR
      return;
    }
    bm = wgid >> 3;                                  // 0..1
    bn = wgid & 7;                                   // 0..7
  }
  const int NT = K >> 5;                      // K tiles of 32

  // ---- staging maps (linear LDS dest = base + lane*16; swizzled global src)
  const int srow  = tid >> 2;                 // 0..127 (chunk j adds 128)
  const int sslot = tid & 3;                  // LDS 16B slot within 64B row
  const int gslot = sslot ^ ((tid >> 3) & 3); // swizzled source slot
  const _Float16* Ag = A + (size_t)(bm * 256 + srow) * K + gslot * 8;
  const _Float16* Bg = B + (size_t)(bn * 256 + srow) * K + gslot * 8;
  const size_t rstride = (size_t)128 * K;
  const int ldst = srow * 32 + sslot * 8;     // halves

  // ---- fragment read offsets (swizzled): slot = lq ^ ((lr>>1)&3)
  const int fswz = (lq ^ ((lr >> 1) & 3)) * 8;
  const int aoff = (wm * 128 + lr) * 32 + fswz;
  const int boff = (wn * 64  + lr) * 32 + fswz;

  floatx4 acc[8][4] = {};

  auto stageA = [&](int t) {
    _Float16* dst = Asmem[t & 3] + ldst;
    const _Float16* src = Ag + (size_t)t * 32;
    gload16(src, dst);
    gload16(src + rstride, dst + 128 * 32);
  };
  auto stageB = [&](int t) {
    _Float16* dst = Bsmem[t & 3] + ldst;
    const _Float16* src = Bg + (size_t)t * 32;
    gload16(src, dst);
    gload16(src + rstride, dst + 128 * 32);
  };

  // ---- prologue: stage tiles 0,1,2 (12 loads); gate tile 0 with vmcnt(8)
  stageA(0); stageB(0);
  if (NT > 1) { stageA(1); stageB(1); }
  if (NT > 2) { stageA(2); stageB(2); }
  if (NT > 2)      { GATE(8); }
  else if (NT > 1) { GATE(4); }
  else             { GATE(0); }
  __builtin_amdgcn_s_barrier();
  MEMFENCE;

  for (int t = 0; t < NT; ++t) {
    const _Float16* As = Asmem[t & 3];
    const _Float16* Bs = Bsmem[t & 3];
    half8 af[4], bf[4], af2[4];

    // ---- phase 0: quadrant mi0-3 --------------------------------------
    #pragma unroll
    for (int mi = 0; mi < 4; ++mi) af[mi] = *(const half8*)&As[aoff + mi * 512];
    #pragma unroll
    for (int ni = 0; ni < 4; ++ni) bf[ni] = *(const half8*)&Bs[boff + ni * 512];
    if (t + 3 < NT) stageA(t + 3);
    MEMFENCE;
    __builtin_amdgcn_s_barrier();
    MEMFENCE;
    __builtin_amdgcn_s_setprio(1);
    #pragma unroll
    for (int mi = 0; mi < 4; ++mi)
      #pragma unroll
      for (int ni = 0; ni < 4; ++ni)
        acc[mi][ni] = __builtin_amdgcn_mfma_f32_16x16x32_f16(
            af[mi], bf[ni], acc[mi][ni], 0, 0, 0);
    __builtin_amdgcn_s_setprio(0);

    // ---- phase 1: quadrant mi4-7 + counted-vmcnt gate for tile t+1 ----
    #pragma unroll
    for (int mi = 0; mi < 4; ++mi)
      af2[mi] = *(const half8*)&As[aoff + (mi + 4) * 512];
    if (t + 3 < NT) stageB(t + 3);
    if (t + 4 <= NT)      { GATE(8); }   // 2 future tiles in flight
    else if (t + 3 == NT) { GATE(4); }   // 1 future tile
    else if (t + 2 == NT) { GATE(0); }   // drain before last tile
    __builtin_amdgcn_s_barrier();
    MEMFENCE;
    __builtin_amdgcn_s_setprio(1);
    #pragma unroll
    for (int mi = 0; mi < 4; ++mi)
      #pragma unroll
      for (int ni = 0; ni < 4; ++ni)
        acc[mi + 4][ni] = __builtin_amdgcn_mfma_f32_16x16x32_f16(
            af2[mi], bf[ni], acc[mi + 4][ni], 0, 0, 0);
    __builtin_amdgcn_s_setprio(0);
  }

  // ---- epilogue.  C/D layout: col = lane&15, row = (lane>>4)*4 + reg
  const int grb = bm * 256 + wm * 128;
  const int gcb = bn * 256 + wn * 64;

  if constexpr (PASS == 0) {
    if (bm < NROW / 256) {             // EPI0: Kx -> DK fp16
      #pragma unroll
      for (int mi = 0; mi < 8; ++mi)
        #pragma unroll
        for (int e = 0; e < 4; ++e) {
          const int gr = grb + mi * 16 + lq * 4 + e;
          const float rni = rn[gr];
          #pragma unroll
          for (int ni = 0; ni < 4; ++ni) {
            const int gc = gcb + ni * 16 + lr;
            const float d = rni + cn[gc] - 2.f * acc[mi][ni][e];
            DKout[(size_t)gr * MIND + gc] = (_Float16)(expf(-fabsf(d)) - CC);
          }
        }
    } else {                           // EPI1: Kreg fp32 (+0.05 I)
      #pragma unroll
      for (int mi = 0; mi < 8; ++mi)
        #pragma unroll
        for (int e = 0; e < 4; ++e) {
          const int gr = grb + mi * 16 + lq * 4 + e;
          const int gr2 = gr - NROW;
          const float rni = rn[gr];    // rn = rnorm||cnorm contiguous
          #pragma unroll
          for (int ni = 0; ni < 4; ++ni) {
            const int gc = gcb + ni * 16 + lr;
            const float d = rni + cn[gc] - 2.f * acc[mi][ni][e];
            float kx = expf(-fabsf(d));
            if (gr2 == gc) kx += 0.05f;
            Cf[(size_t)gr2 * MIND + gc] = kx;
          }
        }
    }
  } else if constexpr (PASS == 1) {
    if (bn < MIND / 256) {             // EPI2: var reduction
      #pragma unroll
      for (int mi = 0; mi < 8; ++mi)
        #pragma unroll
        for (int e = 0; e < 4; ++e) {
          const int gr = grb + mi * 16 + lq * 4 + e;
          float partial = 0.f;
          #pragma unroll
          for (int ni = 0; ni < 4; ++ni) {
            const int gc = gcb + ni * 16 + lr;
            const float tv = acc[mi][ni][e] + CC * u[gc];
            partial += tv * (CC + (float)DK[(size_t)gr * MIND + gc]);
          }
          partial += __shfl_xor(partial, 1);
          partial += __shfl_xor(partial, 2);
          partial += __shfl_xor(partial, 4);
          partial += __shfl_xor(partial, 8);
          if (lr == 0) atomicAdd(&varacc[gr], partial);
        }
    } else {                           // EPI3: x_new
      const int gcb3 = (bn - MIND / 256) * 256 + wn * 64;
      #pragma unroll
      for (int mi = 0; mi < 8; ++mi)
        #pragma unroll
        for (int e = 0; e < 4; ++e) {
          const int gr = grb + mi * 16 + lq * 4 + e;
          const float mrow = (mask[gr] != 0) ? 1.f : 0.f;
          #pragma unroll
          for (int ni = 0; ni < 4; ++ni) {
            const int gc3 = gcb3 + ni * 16 + lr;
            const float v = acc[mi][ni][e] + CC * colsumR[gc3];
            Cf[(size_t)gr * NF + gc3] = (v * stdv[gc3] + meanv[gc3]) * mrow;
          }
        }
    }
  } else {                             // PASS 2: Rt = fp16(ip^T * Kinv)
    #pragma unroll
    for (int mi = 0; mi < 8; ++mi)
      #pragma unroll
      for (int e = 0; e < 4; ++e) {
        const int gr = grb + mi * 16 + lq * 4 + e;
        #pragma unroll
        for (int ni = 0; ni < 4; ++ni) {
          const int gc = gcb + ni * 16 + lr;
          DKout[(size_t)gr * MIND + gc] = (_Float16)acc[mi][ni][e];
        }
      }
  }
}

// ------------------------------------------------- blocked Gauss-Jordan ----
// R10: prep(k+1) merged into the apply(k) launch as 64 extra blocks (grid
// 1088) with POINT-TO-POINT flags (not a grid barrier): apply blocks never
// wait (inputs from previous launch); prep blocks poll fP (P(k+1) from the
// diag-next block) + one per-tile epoch flag.  Deadlock-free: waiters are a
// strict subset; producers never wait.  Fence protocol = R7's empirically
// verified pattern (syncthreads -> threadfence -> agent release store).
// CP/Bsave ping-pong by k parity kills the intra-launch WAR.
// GJ chain: 65 launches -> 34.

__global__ __launch_bounds__(256) void gj_diag(
    float* __restrict__ A, float* __restrict__ Pall, int k)
{
  const int o = k * 64;
  __shared__ float D[64][68];
  const int t = threadIdx.x;
  #pragma unroll
  for (int l = 0; l < 4; ++l) {
    const int v = t + l * 256;
    const int r = v >> 4, c4 = (v & 15) << 2;
    *(float4*)&D[r][c4] = *(const float4*)(A + (size_t)(o + r) * MIND + o + c4);
  }
  __syncthreads();
  const int i = t >> 2, c0 = (t & 3) * 16;
  for (int s = 0; s < 64; ++s) {
    const float p = 1.0f / D[s][s];
    if (t < 64 && t != s) D[s][t] *= p;
    __syncthreads();
    if (i != s) {
      const float f = D[i][s];
      #pragma unroll
      for (int c = c0; c < c0 + 16; c += 4) {
        float4 ds = *(const float4*)&D[s][c];
        float4 di = *(const float4*)&D[i][c];
        di.x -= f * ds.x; di.y -= f * ds.y; di.z -= f * ds.z; di.w -= f * ds.w;
        *(float4*)&D[i][c] = di;
      }
      if (s >= c0 && s < c0 + 16) D[i][s] = -f * p;
    }
    if (t == 0) D[s][s] = p;
    __syncthreads();
  }
  float* P = Pall + k * 4096;
  #pragma unroll
  for (int l = 0; l < 4; ++l) {
    const int v = t + l * 256;
    const int r = v >> 4, c4 = (v & 15) << 2;
    const float4 dv = *(const float4*)&D[r][c4];
    *(float4*)(P + r * 64 + c4) = dv;
    *(float4*)(A + (size_t)(o + r) * MIND + o + c4) = dv;
  }
}

// bootstrap prep(0): bx<32 -> CP_i = A[i][0:64]*P0; bx>=32 -> Bsave copy
__global__ __launch_bounds__(256) void gj_prep(
    const float* __restrict__ A, const float* __restrict__ Pall,
    float* __restrict__ CP, float* __restrict__ Bsave, int k)
{
  const int o = k * 64;
  const int t = threadIdx.x;
  if (blockIdx.x >= 32) {
    const int j0 = (blockIdx.x - 32) * 64;
    #pragma unroll
    for (int l = 0; l < 4; ++l) {
      const int v = t + l * 256;
      const int r = v >> 4, c4 = (v & 15) << 2;
      *(float4*)(Bsave + r * MIND + j0 + c4) =
          *(const float4*)(A + (size_t)(o + r) * MIND + j0 + c4);
    }
    return;
  }
  const int i0 = blockIdx.x * 64;
  if (i0 == o) return;
  const float* P = Pall + k * 4096;
  __shared__ float At[64][68];
  __shared__ float Pl[64][68];
  #pragma unroll
  for (int l = 0; l < 4; ++l) {
    const int v = t + l * 256;
    const int r = v >> 4, c4 = (v & 15) << 2;
    const float4 av = *(const float4*)(A + (size_t)(i0 + r) * MIND + o + c4);
    At[c4 + 0][r] = av.x; At[c4 + 1][r] = av.y;
    At[c4 + 2][r] = av.z; At[c4 + 3][r] = av.w;
    *(float4*)&Pl[r][c4] = *(const float4*)(P + r * 64 + c4);
  }
  __syncthreads();
  const int ty = t >> 4, tx = t & 15;
  float acc[4][4] = {};
  for (int s = 0; s < 64; ++s) {
    const float4 a4 = *(const float4*)&At[s][ty * 4];
    const float4 b4 = *(const float4*)&Pl[s][tx * 4];
    const float a[4] = {a4.x, a4.y, a4.z, a4.w};
    const float b[4] = {b4.x, b4.y, b4.z, b4.w};
    #pragma unroll
    for (int i = 0; i < 4; ++i)
      #pragma unroll
      for (int j = 0; j < 4; ++j) acc[i][j] += a[i] * b[j];
  }
  #pragma unroll
  for (int i = 0; i < 4; ++i) {
    float4 o4; o4.x = acc[i][0]; o4.y = acc[i][1]; o4.z = acc[i][2]; o4.w = acc[i][3];
    *(float4*)(CP + (i0 + ty * 4 + i) * 64 + tx * 4) = o4;
  }
}

// fused apply(k) + prep(k+1).  blockIdx 0..1023 = apply tiles (never wait);
// 1024..1087 = prep(k+1) (poll point-to-point flags).  Grid is 1024 for the
// last iteration (k==31, no prep).
__global__ __launch_bounds__(256) void gj_fused(
    float* __restrict__ A, float* __restrict__ Pall,
    const float* __restrict__ CPr, const float* __restrict__ BSr,
    float* __restrict__ CPw, float* __restrict__ BSw,
    int* __restrict__ fP, int* __restrict__ ttile, int k)
{
  const int o = k * 64;
  const int t = threadIdx.x;
  __shared__ float S1[64 * 68];
  __shared__ float S2[64 * 68];
  #define DD(r, c) S1[(r) * 68 + (c)]

  if (blockIdx.x >= 1024) {            // ---------- prep(k+1) ----------
    const int pb = blockIdx.x - 1024;
    const int o2 = o + 64, g2 = o2 >> 6;
    if (pb >= 32) {                    // Bsave(k+1) col tile jg
      const int jg = pb - 32, j0 = jg * 64;
      if (t == 0)
        while (__hip_atomic_load(&ttile[g2 * 32 + jg], __ATOMIC_ACQUIRE,
                                 __HIP_MEMORY_SCOPE_AGENT) < k + 1)
          __builtin_amdgcn_s_sleep(8);
      __syncthreads();
      #pragma unroll
      for (int l = 0; l < 4; ++l) {
        const int v = t + l * 256;
        const int r = v >> 4, c4 = (v & 15) << 2;
        *(float4*)(BSw + r * MIND + j0 + c4) =
            *(const float4*)(A + (size_t)(o2 + r) * MIND + j0 + c4);
      }
      return;
    }
    const int i0 = pb * 64;            // CP(k+1) row group
    if (i0 == o2) return;
    if (t == 0) {
      while (__hip_atomic_load(fP, __ATOMIC_ACQUIRE,
                               __HIP_MEMORY_SCOPE_AGENT) < k + 2)
        __builtin_amdgcn_s_sleep(8);
      while (__hip_atomic_load(&ttile[pb * 32 + g2], __ATOMIC_ACQUIRE,
                               __HIP_MEMORY_SCOPE_AGENT) < k + 1)
        __builtin_amdgcn_s_sleep(8);
    }
    __syncthreads();
    const float* P = Pall + (size_t)(k + 1) * 4096;
    #pragma unroll
    for (int l = 0; l < 4; ++l) {
      const int v = t + l * 256;
      const int r = v >> 4, c4 = (v & 15) << 2;
      const float4 av = *(const float4*)(A + (size_t)(i0 + r) * MIND + o2 + c4);
      S1[(c4 + 0) * 68 + r] = av.x; S1[(c4 + 1) * 68 + r] = av.y;
      S1[(c4 + 2) * 68 + r] = av.z; S1[(c4 + 3) * 68 + r] = av.w;
      *(float4*)&S2[r * 68 + c4] = *(const float4*)(P + r * 64 + c4);
    }
    __syncthreads();
    const int ty = t >> 4, tx = t & 15;
    float acc[4][4] = {};
    for (int s = 0; s < 64; ++s) {
      const float4 a4 = *(const float4*)&S1[s * 68 + ty * 4];
      const float4 b4 = *(const float4*)&S2[s * 68 + tx * 4];
      const float a[4] = {a4.x, a4.y, a4.z, a4.w};
      const float b[4] = {b4.x, b4.y, b4.z, b4.w};
      #pragma unroll
      for (int i = 0; i < 4; ++i)
        #pragma unroll
        for (int j = 0; j < 4; ++j) acc[i][j] += a[i] * b[j];
    }
    #pragma unroll
    for (int i = 0; i < 4; ++i) {
      float4 o4; o4.x = acc[i][0]; o4.y = acc[i][1]; o4.z = acc[i][2]; o4.w = acc[i][3];
      *(float4*)(CPw + (i0 + ty * 4 + i) * 64 + tx * 4) = o4;
    }
    return;
  }

  // ------------------------------ apply(k) ------------------------------
  const int ig = blockIdx.x >> 5, jg = blockIdx.x & 31;
  const int i0 = ig * 64, j0 = jg * 64;

  if (i0 == o && j0 == o) return;      // tile holds P(k); nobody polls it

  if (j0 == o) {                       // col: A_io = -CP_i (negated copy)
    #pragma unroll
    for (int l = 0; l < 4; ++l) {
      const int v = t + l * 256;
      const int r = v >> 4, c4 = (v & 15) << 2;
      float4 x = *(const float4*)(CPr + (i0 + r) * 64 + c4);
      x.x = -x.x; x.y = -x.y; x.z = -x.z; x.w = -x.w;
      *(float4*)(A + (size_t)(i0 + r) * MIND + o + c4) = x;
    }
    __syncthreads();
    if (t == 0) {
      __threadfence();
      __hip_atomic_store(&ttile[ig * 32 + jg], k + 1, __ATOMIC_RELEASE,
                         __HIP_MEMORY_SCOPE_AGENT);
    }
    return;
  }

  const bool isrow = (i0 == o);
  const float* Lsrc = isrow ? (Pall + (size_t)k * 4096) : (CPr + i0 * 64);
  #pragma unroll
  for (int l = 0; l < 4; ++l) {
    const int v = t + l * 256;
    const int r = v >> 4, c4 = (v & 15) << 2;
    const float4 lv = *(const float4*)(Lsrc + r * 64 + c4);
    S1[(c4 + 0) * 68 + r] = lv.x; S1[(c4 + 1) * 68 + r] = lv.y;
    S1[(c4 + 2) * 68 + r] = lv.z; S1[(c4 + 3) * 68 + r] = lv.w;
    *(float4*)&S2[r * 68 + c4] = *(const float4*)(BSr + r * MIND + j0 + c4);
  }
  __syncthreads();
  const int ty = t >> 4, tx = t & 15;
  float acc[4][4] = {};
  for (int s = 0; s < 64; ++s) {
    const float4 a4 = *(const float4*)&S1[s * 68 + ty * 4];
    const float4 b4 = *(const float4*)&S2[s * 68 + tx * 4];
    const float a[4] = {a4.x, a4.y, a4.z, a4.w};
    const float b[4] = {b4.x, b4.y, b4.z, b4.w};
    #pragma unroll
    for (int i = 0; i < 4; ++i)
      #pragma unroll
      for (int j = 0; j < 4; ++j) acc[i][j] += a[i] * b[j];
  }

  if (isrow) {                         // row panel: A_oj = P * Bsave_j
    #pragma unroll
    for (int i = 0; i < 4; ++i) {
      float4 o4; o4.x = acc[i][0]; o4.y = acc[i][1]; o4.z = acc[i][2]; o4.w = acc[i][3];
      *(float4*)(A + (size_t)(o + ty * 4 + i) * MIND + j0 + tx * 4) = o4;
    }
    __syncthreads();
    if (t == 0) {
      __threadfence();
      __hip_atomic_store(&ttile[ig * 32 + jg], k + 1, __ATOMIC_RELEASE,
                         __HIP_MEMORY_SCOPE_AGENT);
    }
    return;
  }

  const bool isdiagnext = (i0 == o + 64) && (j0 == o + 64);
  if (!isdiagnext) {                   // big: A_ij -= CP_i * Bsave_j
    #pragma unroll
    for (int i = 0; i < 4; ++i) {
      float* cp = A + (size_t)(i0 + ty * 4 + i) * MIND + j0 + tx * 4;
      float4 cv = *(const float4*)cp;
      cv.x -= acc[i][0]; cv.y -= acc[i][1]; cv.z -= acc[i][2]; cv.w -= acc[i][3];
      *(float4*)cp = cv;
    }
    __syncthreads();
    if (t == 0) {
      __threadfence();
      __hip_atomic_store(&ttile[ig * 32 + jg], k + 1, __ATOMIC_RELEASE,
                         __HIP_MEMORY_SCOPE_AGENT);
    }
    return;
  }

  // diag-next: update into LDS, 64-step pivot, emit Pall[k+1] + A, flags
  __syncthreads();                     // S1 readers done
  #pragma unroll
  for (int i = 0; i < 4; ++i) {
    const float4 cv = *(const float4*)(A + (size_t)(i0 + ty * 4 + i) * MIND + j0 + tx * 4);
    DD(ty * 4 + i, tx * 4 + 0) = cv.x - acc[i][0];
    DD(ty * 4 + i, tx * 4 + 1) = cv.y - acc[i][1];
    DD(ty * 4 + i, tx * 4 + 2) = cv.z - acc[i][2];
    DD(ty * 4 + i, tx * 4 + 3) = cv.w - acc[i][3];
  }
  __syncthreads();
  const int di = t >> 2, c0 = (t & 3) * 16;
  for (int s = 0; s < 64; ++s) {
    const float p = 1.0f / DD(s, s);
    if (t < 64 && t != s) DD(s, t) *= p;
    __syncthreads();
    if (di != s) {
      const float f = DD(di, s);
      #pragma unroll
      for (int c = c0; c < c0 + 16; c += 4) {
        float4 ds = *(const float4*)&DD(s, c);
        float4 dv = *(const float4*)&DD(di, c);
        dv.x -= f * ds.x; dv.y -= f * ds.y; dv.z -= f * ds.z; dv.w -= f * ds.w;
        *(float4*)&DD(di, c) = dv;
      }
      if (s >= c0 && s < c0 + 16) DD(di, s) = -f * p;
    }
    if (t == 0) DD(s, s) = p;
    __syncthreads();
  }
  float* Pn = Pall + (size_t)(k + 1) * 4096;
  #pragma unroll
  for (int l = 0; l < 4; ++l) {
    const int v = t + l * 256;
    const int r = v >> 4, c4 = (v & 15) << 2;
    const float4 dv = *(const float4*)&DD(r, c4);
    *(float4*)(Pn + r * 64 + c4) = dv;
    *(float4*)(A + (size_t)(i0 + r) * MIND + j0 + c4) = dv;
  }
  __syncthreads();
  if (t == 0) {
    __threadfence();
    __hip_atomic_store(&ttile[ig * 32 + jg], k + 1, __ATOMIC_RELEASE,
                       __HIP_MEMORY_SCOPE_AGENT);
    __hip_atomic_store(fP, k + 2, __ATOMIC_RELEASE,
                       __HIP_MEMORY_SCOPE_AGENT);
  }
  #undef DD
}

// ----------------------------------------------------------- helpers -------
// u = rowsum(Ai) AND Kih = fp16(Ai) in one pass
__global__ __launch_bounds__(256) void rowsum_cast(
    const float* __restrict__ Ai, float* __restrict__ u,
    _Float16* __restrict__ Kih)
{
  const int row = blockIdx.x * 4 + (threadIdx.x >> 6);
  const int lane = threadIdx.x & 63;
  const float* src = Ai + (size_t)row * MIND;
  _Float16* dst = Kih + (size_t)row * MIND;
  float s = 0.f;
  #pragma unroll
  for (int it = 0; it < 8; ++it) {
    const int c = it * 256 + lane * 4;
    const float4 v = *(const float4*)(src + c);
    s += v.x + v.y + v.z + v.w;
    half4v h; h.x = (_Float16)v.x; h.y = (_Float16)v.y;
    h.z = (_Float16)v.z; h.w = (_Float16)v.w;
    *(half4v*)(dst + c) = h;
  }
  #pragma unroll
  for (int off = 32; off; off >>= 1) s += __shfl_xor(s, off);
  if (lane == 0) u[row] = s;
}

__global__ __launch_bounds__(256) void var_finalize(
    const float* __restrict__ varacc, const int* __restrict__ mask,
    float* __restrict__ outv)
{
  const int i = blockIdx.x * 256 + threadIdx.x;
  const float m = (mask[i] != 0) ? 1.f : 0.f;
  outv[i] = (1.0f - varacc[i]) * m;
}

}  // namespace

extern "C" void kernel_launch(void* const* d_in, const int* in_sizes, int n_in,
                              void* d_out, int out_size, void* d_ws, size_t ws_size,
                              hipStream_t stream)
{
  (void)in_sizes; (void)n_in; (void)out_size; (void)ws_size;
  const float* x     = (const float*)d_in[0];
  const int*   mask  = (const int*)d_in[1];
  const float* ip    = (const float*)d_in[2];
  const float* gamma = (const float*)d_in[3];
  float* out = (float*)d_out;

  // ---- workspace layout (zeroed region = [0, 19456) floats) ----
  float* w       = (float*)d_ws;
  float* sum     = w;                     // 512
  float* sumsq   = w + 512;               // 512
  float* cnt     = w + 1024;              // 1
  int*   fP      = (int*)(w + 1028);      // 1 int (monotonic P-ready flag)
  int*   ttile   = (int*)(w + 1056);      // 1024 ints (per-tile epoch)
  float* varacc  = w + 2560;              // 16384 -> ends 18944
  float* colsumR = w + 18944;             // 512   -> ends 19456 (memset end)
  float* meanv   = w + 19456;             // 512 (written by make_z block 0)
  float* stdv    = w + 19968;             // 512
  float* u       = w + 20480;             // 2048
  float* rnorm   = w + 22528;             // 16384 } rnorm||cnorm contiguous
  float* cnorm   = w + 38912;             // 2048  } ends 40960
  float* Ai      = w + 40960;             // 2048*2048 (Kreg -> Kinv in place)
  _Float16* ipTh = (_Float16*)(w + 4235264);  // 512*2048 fp16 -> ends 4759552
  float* CP2     = w + 4759552;           // 2048*64  (ping)
  float* Bs2     = w + 4890624;           // 64*2048  (ping)
  float* Pall    = w + 5283840;           // 32*4096 pivot inverses
  float* CP      = w + 5414912;           // 2048*64  (pong)
  float* Bsave   = w + 5545984;           // 64*2048  (pong)
  _Float16* hb   = (_Float16*)(w + 5677056);
  _Float16* Zh   = hb;                    // 16384*512 } Zh||Zih contiguous
  _Float16* Zih  = hb + 8388608;          // 2048*512  }
  _Float16* DK   = hb + 9437184;          // 16384*2048
  _Float16* Kih  = hb + 42991616;         // 2048*2048 } Kih||Rt contiguous
  _Float16* Rt   = hb + 47185920;         // 512*2048  }

  hipMemsetAsync(w, 0, 19456 * sizeof(float), stream);

  stats_kernel<<<256, 256, 0, stream>>>(x, mask, sum, sumsq, cnt);
  // make_z: finalize folded per-thread; +256 blocks doing ipTh transpose
  make_z<<<NROW + MIND + 256, 256, 0, stream>>>(
      x, mask, ip, sum, sumsq, cnt, gamma,
      Zh, Zih, rnorm, cnorm, meanv, stdv, ipTh);

  // PASS 0: A' = [Zh;Zih] -> DK (bm<64) + Kreg/Ai (bm>=64), XCD-swizzled
  mfma_gemm256f<0><<<dim3(MIND / 256, (NROW + MIND) / 256), 512, 0, stream>>>(
      Zh, Zih, NF, rnorm, cnorm,
      DK, Ai, nullptr, nullptr, nullptr, nullptr, nullptr, nullptr, nullptr);

  // Gauss-Jordan: bootstrap (diag + prep0) + 32 fused apply/prep launches
  float* CPb[2] = {CP, CP2};
  float* BSb[2] = {Bsave, Bs2};
  gj_diag<<<1, 256, 0, stream>>>(Ai, Pall, 0);
  gj_prep<<<64, 256, 0, stream>>>(Ai, Pall, CPb[0], BSb[0], 0);
  for (int k = 0; k < 32; ++k) {
    const int nb = (k < 31) ? 1088 : 1024;
    gj_fused<<<nb, 256, 0, stream>>>(
        Ai, Pall, CPb[k & 1], BSb[k & 1],
        CPb[(k + 1) & 1], BSb[(k + 1) & 1], fP, ttile, k);
  }

  // u + Kih (one Ai pass); PASS2: Rt = fp16(ip^T Kinv) + fused colsumR
  rowsum_cast<<<MIND / 4, 256, 0, stream>>>(Ai, u, Kih);
  mfma_gemm256f<2><<<dim3(8, 6), 512, 0, stream>>>(
      ipTh, Kih, MIND, ip, nullptr,
      Rt, nullptr, nullptr, u, colsumR, nullptr, nullptr, nullptr, nullptr);

  // PASS 1: B' = [Kih;Rt] -> varacc (bn<8) + x_new (bn>=8), XCD-swizzled
  mfma_gemm256f<1><<<dim3((MIND + NF) / 256, NROW / 256), 512, 0, stream>>>(
      DK, Kih, MIND, nullptr, nullptr,
      nullptr, out, DK, u, varacc, colsumR, stdv, meanv, mask);

  var_finalize<<<NROW / 256, 256, 0, stream>>>(varacc, mask, out + (size_t)NROW * NF);
}

// Round 11
// 2060.562 us; speedup vs baseline: 1.2676x; 1.2676x over previous
//
#include <hip/hip_runtime.h>
#include <math.h>
#include <stdint.h>

namespace {

constexpr int NROW = 16384;   // B*A
constexpr int NF   = 512;     // n_in
constexpr int MIND = 2048;    // inducing points
constexpr float CC = 0.98f;   // centering constant: Kx = exp(-d), d ~ 0.004

typedef _Float16 half8 __attribute__((ext_vector_type(8)));
typedef _Float16 half4v __attribute__((ext_vector_type(4)));
typedef float floatx4 __attribute__((ext_vector_type(4)));

__device__ __forceinline__ void gload16(const void* g, void* l) {
  __builtin_amdgcn_global_load_lds(
      (__attribute__((address_space(1))) void*)g,
      (__attribute__((address_space(3))) void*)l, 16, 0, 0);
}

#define MEMFENCE asm volatile("" ::: "memory")
#define GATE(N) asm volatile("s_waitcnt vmcnt(" #N ")" ::: "memory")

// ---------------------------------------------------------------- stats ----
__global__ __launch_bounds__(256) void stats_kernel(
    const float* __restrict__ x, const int* __restrict__ mask,
    float* __restrict__ sum, float* __restrict__ sumsq, float* __restrict__ cnt)
{
  const int t = threadIdx.x;
  const int row0 = blockIdx.x * 64;
  float s0 = 0.f, s1 = 0.f, q0 = 0.f, q1 = 0.f, c = 0.f;
  for (int r = 0; r < 64; ++r) {
    const int row = row0 + r;
    const float m = (mask[row] != 0) ? 1.f : 0.f;
    const float v0 = x[(size_t)row * NF + t];
    const float v1 = x[(size_t)row * NF + t + 256];
    s0 += m * v0; q0 += m * v0 * v0;
    s1 += m * v1; q1 += m * v1 * v1;
    c += m;
  }
  atomicAdd(&sum[t], s0);        atomicAdd(&sum[t + 256], s1);
  atomicAdd(&sumsq[t], q0);      atomicAdd(&sumsq[t + 256], q1);
  if (t == 0) atomicAdd(cnt, c);
}

// z rows (masked, normalized, /g2) fp16 + zi rows fp16 + fp32 norms of the
// fp16-ROUNDED values.  Folded in (proven in R10): per-thread finalize_stats
// (block 0 persists meanv/stdv) and ip^T fp16 transpose (256 extra blocks).
__global__ __launch_bounds__(256) void make_z(
    const float* __restrict__ x, const int* __restrict__ mask,
    const float* __restrict__ ip, const float* __restrict__ sum,
    const float* __restrict__ sumsq, const float* __restrict__ cnt,
    const float* __restrict__ gamma,
    _Float16* __restrict__ Zh, _Float16* __restrict__ Zih,
    float* __restrict__ rnorm, float* __restrict__ cnorm,
    float* __restrict__ meanv, float* __restrict__ stdv,
    _Float16* __restrict__ ipTh)
{
  __shared__ float T[64][65];
  const int row = blockIdx.x;
  const int t = threadIdx.x;

  if (row >= NROW + MIND) {            // ---- ipTh tile (256 blocks) ----
    const int idx2 = row - (NROW + MIND);
    const int j0 = (idx2 & 31) * 64, f0 = (idx2 >> 5) * 64;
    #pragma unroll
    for (int l = 0; l < 16; ++l) {
      const int idx = t + l * 256;
      T[idx >> 6][idx & 63] = ip[(size_t)(j0 + (idx >> 6)) * NF + f0 + (idx & 63)];
    }
    __syncthreads();
    #pragma unroll
    for (int l = 0; l < 16; ++l) {
      const int idx = t + l * 256;
      const int fr = idx >> 6, jc = idx & 63;
      ipTh[(size_t)(f0 + fr) * MIND + j0 + jc] = (_Float16)T[jc][fr];
    }
    return;
  }

  // per-thread finalize for cols t and t+256
  const float n = cnt[0];
  float mu[2], zs[2], gi[2];
  #pragma unroll
  for (int h = 0; h < 2; ++h) {
    const int f = t + h * 256;
    const float m0 = sum[f] / n;
    const float var = (sumsq[f] - sum[f] * m0) / (n - 1.0f);
    const float sd = sqrtf(var) + 1e-5f;
    const float g = gamma[f];
    const float g2 = g * g + 0.001f;
    mu[h] = m0; zs[h] = 1.0f / (sd * g2); gi[h] = 1.0f / g2;
    if (row == 0) { meanv[f] = m0; stdv[f] = sd; }
  }

  float v0, v1;
  if (row < NROW) {
    const float m = (mask[row] != 0) ? 1.f : 0.f;
    v0 = (x[(size_t)row * NF + t      ] - mu[0]) * zs[0] * m;
    v1 = (x[(size_t)row * NF + t + 256] - mu[1]) * zs[1] * m;
    const _Float16 h0 = (_Float16)v0, h1 = (_Float16)v1;
    Zh[(size_t)row * NF + t] = h0;
    Zh[(size_t)row * NF + t + 256] = h1;
    v0 = (float)h0; v1 = (float)h1;
  } else {
    const int r = row - NROW;
    v0 = ip[(size_t)r * NF + t      ] * gi[0];
    v1 = ip[(size_t)r * NF + t + 256] * gi[1];
    const _Float16 h0 = (_Float16)v0, h1 = (_Float16)v1;
    Zih[(size_t)r * NF + t] = h0;
    Zih[(size_t)r * NF + t + 256] = h1;
    v0 = (float)h0; v1 = (float)h1;
  }
  float nrm = v0 * v0 + v1 * v1;
  #pragma unroll
  for (int off = 32; off; off >>= 1) nrm += __shfl_xor(nrm, off);
  if ((t & 63) == 0) T[0][t >> 6] = nrm;
  __syncthreads();
  if (t == 0) {
    const float s = T[0][0] + T[0][1] + T[0][2] + T[0][3];
    if (row < NROW) rnorm[row] = s; else cnorm[row - NROW] = s;
  }
}

// ------------------------------------------------- 256x256 deep-pipe GEMM --
// (R5 proven structure: fused-by-concatenation, XCD swizzle, LDS slot
// swizzle, counted vmcnt(8) 4-buffer pipeline.)
// PASS 0: A' = [Zh;Zih], B = Zih, grid (8,72): DK (bm<64) + Kreg (bm>=64)
// PASS 1: A = DK, B' = [Kih;Rt], grid (10,64): varacc (bn<8) + x_new
// PASS 2: A = ipTh, B = Kih, grid (8,6): wgid<16 -> Rt = fp16(ip^T Kinv)
//         (Kinv symmetry); wgid>=16 (32 blocks) -> colsumR = ip^T u (fused)
template <int PASS>
__global__ __launch_bounds__(512, 2) void mfma_gemm256f(
    const _Float16* __restrict__ A, const _Float16* __restrict__ B, int K,
    const float* __restrict__ rn, const float* __restrict__ cn,
    _Float16* __restrict__ DKout, float* __restrict__ Cf,
    const _Float16* __restrict__ DK, const float* __restrict__ u,
    float* __restrict__ varacc,
    const float* __restrict__ colsumR, const float* __restrict__ stdv,
    const float* __restrict__ meanv, const int* __restrict__ mask)
{
  __shared__ __align__(16) _Float16 Asmem[4][256 * 32];
  __shared__ __align__(16) _Float16 Bsmem[4][256 * 32];

  const int tid = threadIdx.x;
  const int w = tid >> 6, L = tid & 63;
  const int wm = w >> 2, wn = w & 3;          // 2 x 4 waves
  const int lq = L >> 4, lr = L & 15;
  // ---- XCD-aware remap (T1): same-bm blocks contiguous on one XCD ----
  int bn, bm;
  if constexpr (PASS == 0) {
    const int wgid = blockIdx.y * 8 + blockIdx.x;    // grid (8,72)
    const int xcd = wgid & 7, q = wgid >> 3;         // q: 0..71
    bm = xcd + 8 * (q >> 3);                         // 0..71, bijective
    bn = q & 7;                                      // 0..7
  } else if constexpr (PASS == 1) {
    const int wgid = blockIdx.y * 10 + blockIdx.x;   // grid (10,64)
    const int xcd = wgid & 7, q = wgid >> 3;         // q: 0..79
    bm = xcd + 8 * (q / 10);                         // 0..63, bijective
    bn = q % 10;                                     // 0..9
  } else {
    const int wgid = blockIdx.y * 8 + blockIdx.x;    // grid (8,6) = 48
    if (wgid >= 16) {                                // fused colsum_u
      const int r0 = (wgid - 16) * 64;
      float s = 0.f;
      for (int r = 0; r < 64; ++r)
        s += u[r0 + r] * rn[(size_t)(r0 + r) * NF + tid];  // rn carries ip
      atomicAdd(&varacc[tid], s);                    // varacc carries colsumR
      return;
    }
    bm = wgid >> 3;                                  // 0..1
    bn = wgid & 7;                                   // 0..7
  }
  const int NT = K >> 5;                      // K tiles of 32

  // ---- staging maps (linear LDS dest = base + lane*16; swizzled global src)
  const int srow  = tid >> 2;                 // 0..127 (chunk j adds 128)
  const int sslot = tid & 3;                  // LDS 16B slot within 64B row
  const int gslot = sslot ^ ((tid >> 3) & 3); // swizzled source slot
  const _Float16* Ag = A + (size_t)(bm * 256 + srow) * K + gslot * 8;
  const _Float16* Bg = B + (size_t)(bn * 256 + srow) * K + gslot * 8;
  const size_t rstride = (size_t)128 * K;
  const int ldst = srow * 32 + sslot * 8;     // halves

  // ---- fragment read offsets (swizzled): slot = lq ^ ((lr>>1)&3)
  const int fswz = (lq ^ ((lr >> 1) & 3)) * 8;
  const int aoff = (wm * 128 + lr) * 32 + fswz;
  const int boff = (wn * 64  + lr) * 32 + fswz;

  floatx4 acc[8][4] = {};

  auto stageA = [&](int t) {
    _Float16* dst = Asmem[t & 3] + ldst;
    const _Float16* src = Ag + (size_t)t * 32;
    gload16(src, dst);
    gload16(src + rstride, dst + 128 * 32);
  };
  auto stageB = [&](int t) {
    _Float16* dst = Bsmem[t & 3] + ldst;
    const _Float16* src = Bg + (size_t)t * 32;
    gload16(src, dst);
    gload16(src + rstride, dst + 128 * 32);
  };

  // ---- prologue: stage tiles 0,1,2 (12 loads); gate tile 0 with vmcnt(8)
  stageA(0); stageB(0);
  if (NT > 1) { stageA(1); stageB(1); }
  if (NT > 2) { stageA(2); stageB(2); }
  if (NT > 2)      { GATE(8); }
  else if (NT > 1) { GATE(4); }
  else             { GATE(0); }
  __builtin_amdgcn_s_barrier();
  MEMFENCE;

  for (int t = 0; t < NT; ++t) {
    const _Float16* As = Asmem[t & 3];
    const _Float16* Bs = Bsmem[t & 3];
    half8 af[4], bf[4], af2[4];

    // ---- phase 0: quadrant mi0-3 --------------------------------------
    #pragma unroll
    for (int mi = 0; mi < 4; ++mi) af[mi] = *(const half8*)&As[aoff + mi * 512];
    #pragma unroll
    for (int ni = 0; ni < 4; ++ni) bf[ni] = *(const half8*)&Bs[boff + ni * 512];
    if (t + 3 < NT) stageA(t + 3);
    MEMFENCE;
    __builtin_amdgcn_s_barrier();
    MEMFENCE;
    __builtin_amdgcn_s_setprio(1);
    #pragma unroll
    for (int mi = 0; mi < 4; ++mi)
      #pragma unroll
      for (int ni = 0; ni < 4; ++ni)
        acc[mi][ni] = __builtin_amdgcn_mfma_f32_16x16x32_f16(
            af[mi], bf[ni], acc[mi][ni], 0, 0, 0);
    __builtin_amdgcn_s_setprio(0);

    // ---- phase 1: quadrant mi4-7 + counted-vmcnt gate for tile t+1 ----
    #pragma unroll
    for (int mi = 0; mi < 4; ++mi)
      af2[mi] = *(const half8*)&As[aoff + (mi + 4) * 512];
    if (t + 3 < NT) stageB(t + 3);
    if (t + 4 <= NT)      { GATE(8); }   // 2 future tiles in flight
    else if (t + 3 == NT) { GATE(4); }   // 1 future tile
    else if (t + 2 == NT) { GATE(0); }   // drain before last tile
    __builtin_amdgcn_s_barrier();
    MEMFENCE;
    __builtin_amdgcn_s_setprio(1);
    #pragma unroll
    for (int mi = 0; mi < 4; ++mi)
      #pragma unroll
      for (int ni = 0; ni < 4; ++ni)
        acc[mi + 4][ni] = __builtin_amdgcn_mfma_f32_16x16x32_f16(
            af2[mi], bf[ni], acc[mi + 4][ni], 0, 0, 0);
    __builtin_amdgcn_s_setprio(0);
  }

  // ---- epilogue.  C/D layout: col = lane&15, row = (lane>>4)*4 + reg
  const int grb = bm * 256 + wm * 128;
  const int gcb = bn * 256 + wn * 64;

  if constexpr (PASS == 0) {
    if (bm < NROW / 256) {             // EPI0: Kx -> DK fp16
      #pragma unroll
      for (int mi = 0; mi < 8; ++mi)
        #pragma unroll
        for (int e = 0; e < 4; ++e) {
          const int gr = grb + mi * 16 + lq * 4 + e;
          const float rni = rn[gr];
          #pragma unroll
          for (int ni = 0; ni < 4; ++ni) {
            const int gc = gcb + ni * 16 + lr;
            const float d = rni + cn[gc] - 2.f * acc[mi][ni][e];
            DKout[(size_t)gr * MIND + gc] = (_Float16)(expf(-fabsf(d)) - CC);
          }
        }
    } else {                           // EPI1: Kreg fp32 (+0.05 I)
      #pragma unroll
      for (int mi = 0; mi < 8; ++mi)
        #pragma unroll
        for (int e = 0; e < 4; ++e) {
          const int gr = grb + mi * 16 + lq * 4 + e;
          const int gr2 = gr - NROW;
          const float rni = rn[gr];    // rn = rnorm||cnorm contiguous
          #pragma unroll
          for (int ni = 0; ni < 4; ++ni) {
            const int gc = gcb + ni * 16 + lr;
            const float d = rni + cn[gc] - 2.f * acc[mi][ni][e];
            float kx = expf(-fabsf(d));
            if (gr2 == gc) kx += 0.05f;
            Cf[(size_t)gr2 * MIND + gc] = kx;
          }
        }
    }
  } else if constexpr (PASS == 1) {
    if (bn < MIND / 256) {             // EPI2: var reduction
      #pragma unroll
      for (int mi = 0; mi < 8; ++mi)
        #pragma unroll
        for (int e = 0; e < 4; ++e) {
          const int gr = grb + mi * 16 + lq * 4 + e;
          float partial = 0.f;
          #pragma unroll
          for (int ni = 0; ni < 4; ++ni) {
            const int gc = gcb + ni * 16 + lr;
            const float tv = acc[mi][ni][e] + CC * u[gc];
            partial += tv * (CC + (float)DK[(size_t)gr * MIND + gc]);
          }
          partial += __shfl_xor(partial, 1);
          partial += __shfl_xor(partial, 2);
          partial += __shfl_xor(partial, 4);
          partial += __shfl_xor(partial, 8);
          if (lr == 0) atomicAdd(&varacc[gr], partial);
        }
    } else {                           // EPI3: x_new
      const int gcb3 = (bn - MIND / 256) * 256 + wn * 64;
      #pragma unroll
      for (int mi = 0; mi < 8; ++mi)
        #pragma unroll
        for (int e = 0; e < 4; ++e) {
          const int gr = grb + mi * 16 + lq * 4 + e;
          const float mrow = (mask[gr] != 0) ? 1.f : 0.f;
          #pragma unroll
          for (int ni = 0; ni < 4; ++ni) {
            const int gc3 = gcb3 + ni * 16 + lr;
            const float v = acc[mi][ni][e] + CC * colsumR[gc3];
            Cf[(size_t)gr * NF + gc3] = (v * stdv[gc3] + meanv[gc3]) * mrow;
          }
        }
    }
  } else {                             // PASS 2: Rt = fp16(ip^T * Kinv)
    #pragma unroll
    for (int mi = 0; mi < 8; ++mi)
      #pragma unroll
      for (int e = 0; e < 4; ++e) {
        const int gr = grb + mi * 16 + lq * 4 + e;
        #pragma unroll
        for (int ni = 0; ni < 4; ++ni) {
          const int gc = gcb + ni * 16 + lr;
          DKout[(size_t)gr * MIND + gc] = (_Float16)acc[mi][ni][e];
        }
      }
  }
}

// ------------------------------------------------- blocked Gauss-Jordan ----
// R9 proven version (best: 2032 us).  0-for-6 on restructurings; frozen.
// 2 launches/iter.  Per iter k (o = 64k):
//   gj_apply: row A_oj = P*Bsave_j; col A_io = -CP_i; big A_ij -= CP_i*Bsave_j;
//             block (o+64,o+64) also runs the 64-step pivot loop -> Pall[k+1]
//   gj_prep:  CP_i = A[i][o']*P';  Bsave = copy of row panel A[o'][:]
// Bootstrap: gj_diag computes Pall[0] from A_00.

__global__ __launch_bounds__(256) void gj_diag(
    float* __restrict__ A, float* __restrict__ Pall, int k)
{
  const int o = k * 64;
  __shared__ float D[64][68];
  const int t = threadIdx.x;
  #pragma unroll
  for (int l = 0; l < 4; ++l) {
    const int v = t + l * 256;
    const int r = v >> 4, c4 = (v & 15) << 2;
    *(float4*)&D[r][c4] = *(const float4*)(A + (size_t)(o + r) * MIND + o + c4);
  }
  __syncthreads();
  const int i = t >> 2, c0 = (t & 3) * 16;
  for (int s = 0; s < 64; ++s) {
    const float p = 1.0f / D[s][s];
    if (t < 64 && t != s) D[s][t] *= p;
    __syncthreads();
    if (i != s) {
      const float f = D[i][s];
      #pragma unroll
      for (int c = c0; c < c0 + 16; c += 4) {
        float4 ds = *(const float4*)&D[s][c];
        float4 di = *(const float4*)&D[i][c];
        di.x -= f * ds.x; di.y -= f * ds.y; di.z -= f * ds.z; di.w -= f * ds.w;
        *(float4*)&D[i][c] = di;
      }
      if (s >= c0 && s < c0 + 16) D[i][s] = -f * p;
    }
    if (t == 0) D[s][s] = p;
    __syncthreads();
  }
  float* P = Pall + k * 4096;
  #pragma unroll
  for (int l = 0; l < 4; ++l) {
    const int v = t + l * 256;
    const int r = v >> 4, c4 = (v & 15) << 2;
    const float4 dv = *(const float4*)&D[r][c4];
    *(float4*)(P + r * 64 + c4) = dv;
    *(float4*)(A + (size_t)(o + r) * MIND + o + c4) = dv;
  }
}

// 64 blocks: bx<32 -> CP_i = A[i][o]*P (skip i==o); bx>=32 -> Bsave row copy
__global__ __launch_bounds__(256) void gj_prep(
    const float* __restrict__ A, const float* __restrict__ Pall,
    float* __restrict__ CP, float* __restrict__ Bsave, int k)
{
  const int o = k * 64;
  const int t = threadIdx.x;
  if (blockIdx.x >= 32) {
    const int j0 = (blockIdx.x - 32) * 64;
    #pragma unroll
    for (int l = 0; l < 4; ++l) {
      const int v = t + l * 256;
      const int r = v >> 4, c4 = (v & 15) << 2;
      *(float4*)(Bsave + r * MIND + j0 + c4) =
          *(const float4*)(A + (size_t)(o + r) * MIND + j0 + c4);
    }
    return;
  }
  const int i0 = blockIdx.x * 64;
  if (i0 == o) return;
  const float* P = Pall + k * 4096;
  __shared__ float At[64][68];   // At[s][r] = A[i0+r][o+s]
  __shared__ float Pl[64][68];   // Pl[s][c] = P[s][c]
  #pragma unroll
  for (int l = 0; l < 4; ++l) {
    const int v = t + l * 256;
    const int r = v >> 4, c4 = (v & 15) << 2;
    const float4 av = *(const float4*)(A + (size_t)(i0 + r) * MIND + o + c4);
    At[c4 + 0][r] = av.x; At[c4 + 1][r] = av.y;
    At[c4 + 2][r] = av.z; At[c4 + 3][r] = av.w;
    *(float4*)&Pl[r][c4] = *(const float4*)(P + r * 64 + c4);
  }
  __syncthreads();
  const int ty = t >> 4, tx = t & 15;
  float acc[4][4] = {};
  for (int s = 0; s < 64; ++s) {
    const float4 a4 = *(const float4*)&At[s][ty * 4];
    const float4 b4 = *(const float4*)&Pl[s][tx * 4];
    const float a[4] = {a4.x, a4.y, a4.z, a4.w};
    const float b[4] = {b4.x, b4.y, b4.z, b4.w};
    #pragma unroll
    for (int i = 0; i < 4; ++i)
      #pragma unroll
      for (int j = 0; j < 4; ++j) acc[i][j] += a[i] * b[j];
  }
  #pragma unroll
  for (int i = 0; i < 4; ++i) {
    float4 o4; o4.x = acc[i][0]; o4.y = acc[i][1]; o4.z = acc[i][2]; o4.w = acc[i][3];
    *(float4*)(CP + (i0 + ty * 4 + i) * 64 + tx * 4) = o4;
  }
}

__global__ __launch_bounds__(256) void gj_apply(
    float* __restrict__ A, float* __restrict__ Pall,
    const float* __restrict__ CP, const float* __restrict__ Bsave, int k)
{
  const int o = k * 64;
  const int i0 = blockIdx.y * 64, j0 = blockIdx.x * 64;
  const int t = threadIdx.x;

  if (i0 == o && j0 == o) return;

  if (j0 == o) {                       // col: A_io = -CP_i (negated copy)
    #pragma unroll
    for (int l = 0; l < 4; ++l) {
      const int v = t + l * 256;
      const int r = v >> 4, c4 = (v & 15) << 2;
      float4 x = *(const float4*)(CP + (i0 + r) * 64 + c4);
      x.x = -x.x; x.y = -x.y; x.z = -x.z; x.w = -x.w;
      *(float4*)(A + (size_t)(i0 + r) * MIND + o + c4) = x;
    }
    return;
  }

  __shared__ float S1[64 * 68];   // Lt (transposed left op); later D for diag
  __shared__ float S2[64 * 68];   // Bsave tile
  #define DD(r, c) S1[(r) * 68 + (c)]

  const bool isrow = (i0 == o);
  const float* Lsrc = isrow ? (Pall + k * 4096) : (CP + i0 * 64);
  #pragma unroll
  for (int l = 0; l < 4; ++l) {
    const int v = t + l * 256;
    const int r = v >> 4, c4 = (v & 15) << 2;
    const float4 lv = *(const float4*)(Lsrc + r * 64 + c4);
    S1[(c4 + 0) * 68 + r] = lv.x; S1[(c4 + 1) * 68 + r] = lv.y;
    S1[(c4 + 2) * 68 + r] = lv.z; S1[(c4 + 3) * 68 + r] = lv.w;
    *(float4*)&S2[r * 68 + c4] = *(const float4*)(Bsave + r * MIND + j0 + c4);
  }
  __syncthreads();
  const int ty = t >> 4, tx = t & 15;
  float acc[4][4] = {};
  for (int s = 0; s < 64; ++s) {
    const float4 a4 = *(const float4*)&S1[s * 68 + ty * 4];
    const float4 b4 = *(const float4*)&S2[s * 68 + tx * 4];
    const float a[4] = {a4.x, a4.y, a4.z, a4.w};
    const float b[4] = {b4.x, b4.y, b4.z, b4.w};
    #pragma unroll
    for (int i = 0; i < 4; ++i)
      #pragma unroll
      for (int j = 0; j < 4; ++j) acc[i][j] += a[i] * b[j];
  }

  if (isrow) {                         // A_oj = P * Bsave_j
    #pragma unroll
    for (int i = 0; i < 4; ++i) {
      float4 o4; o4.x = acc[i][0]; o4.y = acc[i][1]; o4.z = acc[i][2]; o4.w = acc[i][3];
      *(float4*)(A + (size_t)(o + ty * 4 + i) * MIND + j0 + tx * 4) = o4;
    }
    return;
  }

  const bool isdiagnext = (i0 == o + 64) && (j0 == o + 64);
  if (!isdiagnext) {                   // big: A_ij -= CP_i * Bsave_j
    #pragma unroll
    for (int i = 0; i < 4; ++i) {
      float* cp = A + (size_t)(i0 + ty * 4 + i) * MIND + j0 + tx * 4;
      float4 cv = *(const float4*)cp;
      cv.x -= acc[i][0]; cv.y -= acc[i][1]; cv.z -= acc[i][2]; cv.w -= acc[i][3];
      *(float4*)cp = cv;
    }
    return;
  }

  // diag-next: update into LDS, run 64-step pivot loop, emit Pall[k+1] + A
  __syncthreads();                     // S1 readers done
  #pragma unroll
  for (int i = 0; i < 4; ++i) {
    const float4 cv = *(const float4*)(A + (size_t)(i0 + ty * 4 + i) * MIND + j0 + tx * 4);
    DD(ty * 4 + i, tx * 4 + 0) = cv.x - acc[i][0];
    DD(ty * 4 + i, tx * 4 + 1) = cv.y - acc[i][1];
    DD(ty * 4 + i, tx * 4 + 2) = cv.z - acc[i][2];
    DD(ty * 4 + i, tx * 4 + 3) = cv.w - acc[i][3];
  }
  __syncthreads();
  const int di = t >> 2, c0 = (t & 3) * 16;
  for (int s = 0; s < 64; ++s) {
    const float p = 1.0f / DD(s, s);
    if (t < 64 && t != s) DD(s, t) *= p;
    __syncthreads();
    if (di != s) {
      const float f = DD(di, s);
      #pragma unroll
      for (int c = c0; c < c0 + 16; c += 4) {
        float4 ds = *(const float4*)&DD(s, c);
        float4 dv = *(const float4*)&DD(di, c);
        dv.x -= f * ds.x; dv.y -= f * ds.y; dv.z -= f * ds.z; dv.w -= f * ds.w;
        *(float4*)&DD(di, c) = dv;
      }
      if (s >= c0 && s < c0 + 16) DD(di, s) = -f * p;
    }
    if (t == 0) DD(s, s) = p;
    __syncthreads();
  }
  float* Pn = Pall + (k + 1) * 4096;
  #pragma unroll
  for (int l = 0; l < 4; ++l) {
    const int v = t + l * 256;
    const int r = v >> 4, c4 = (v & 15) << 2;
    const float4 dv = *(const float4*)&DD(r, c4);
    *(float4*)(Pn + r * 64 + c4) = dv;
    *(float4*)(A + (size_t)(i0 + r) * MIND + j0 + c4) = dv;
  }
  #undef DD
}

// ----------------------------------------------------------- helpers -------
// u = rowsum(Ai) AND Kih = fp16(Ai) in one pass
__global__ __launch_bounds__(256) void rowsum_cast(
    const float* __restrict__ Ai, float* __restrict__ u,
    _Float16* __restrict__ Kih)
{
  const int row = blockIdx.x * 4 + (threadIdx.x >> 6);
  const int lane = threadIdx.x & 63;
  const float* src = Ai + (size_t)row * MIND;
  _Float16* dst = Kih + (size_t)row * MIND;
  float s = 0.f;
  #pragma unroll
  for (int it = 0; it < 8; ++it) {
    const int c = it * 256 + lane * 4;
    const float4 v = *(const float4*)(src + c);
    s += v.x + v.y + v.z + v.w;
    half4v h; h.x = (_Float16)v.x; h.y = (_Float16)v.y;
    h.z = (_Float16)v.z; h.w = (_Float16)v.w;
    *(half4v*)(dst + c) = h;
  }
  #pragma unroll
  for (int off = 32; off; off >>= 1) s += __shfl_xor(s, off);
  if (lane == 0) u[row] = s;
}

__global__ __launch_bounds__(256) void var_finalize(
    const float* __restrict__ varacc, const int* __restrict__ mask,
    float* __restrict__ outv)
{
  const int i = blockIdx.x * 256 + threadIdx.x;
  const float m = (mask[i] != 0) ? 1.f : 0.f;
  outv[i] = (1.0f - varacc[i]) * m;
}

}  // namespace

extern "C" void kernel_launch(void* const* d_in, const int* in_sizes, int n_in,
                              void* d_out, int out_size, void* d_ws, size_t ws_size,
                              hipStream_t stream)
{
  (void)in_sizes; (void)n_in; (void)out_size; (void)ws_size;
  const float* x     = (const float*)d_in[0];
  const int*   mask  = (const int*)d_in[1];
  const float* ip    = (const float*)d_in[2];
  const float* gamma = (const float*)d_in[3];
  float* out = (float*)d_out;

  // ---- workspace layout (zeroed region = [0, 19456) floats) ----
  float* w       = (float*)d_ws;
  float* sum     = w;                     // 512
  float* sumsq   = w + 512;               // 512
  float* cnt     = w + 1024;              // 1
  float* varacc  = w + 2560;              // 16384 -> ends 18944
  float* colsumR = w + 18944;             // 512   -> ends 19456 (memset end)
  float* meanv   = w + 19456;             // 512 (written by make_z block 0)
  float* stdv    = w + 19968;             // 512
  float* u       = w + 20480;             // 2048
  float* rnorm   = w + 22528;             // 16384 } rnorm||cnorm contiguous
  float* cnorm   = w + 38912;             // 2048  } ends 40960
  float* Ai      = w + 40960;             // 2048*2048 (Kreg -> Kinv in place)
  _Float16* ipTh = (_Float16*)(w + 4235264);  // 512*2048 fp16 -> ends 4759552
  float* Pall    = w + 5283840;           // 32*4096 pivot inverses
  float* CP      = w + 5414912;           // 2048*64
  float* Bsave   = w + 5545984;           // 64*2048
  _Float16* hb   = (_Float16*)(w + 5677056);
  _Float16* Zh   = hb;                    // 16384*512 } Zh||Zih contiguous
  _Float16* Zih  = hb + 8388608;          // 2048*512  }
  _Float16* DK   = hb + 9437184;          // 16384*2048
  _Float16* Kih  = hb + 42991616;         // 2048*2048 } Kih||Rt contiguous
  _Float16* Rt   = hb + 47185920;         // 512*2048  }

  hipMemsetAsync(w, 0, 19456 * sizeof(float), stream);

  stats_kernel<<<256, 256, 0, stream>>>(x, mask, sum, sumsq, cnt);
  // make_z: finalize folded per-thread; +256 blocks doing ipTh transpose
  make_z<<<NROW + MIND + 256, 256, 0, stream>>>(
      x, mask, ip, sum, sumsq, cnt, gamma,
      Zh, Zih, rnorm, cnorm, meanv, stdv, ipTh);

  // PASS 0: A' = [Zh;Zih] -> DK (bm<64) + Kreg/Ai (bm>=64), XCD-swizzled
  mfma_gemm256f<0><<<dim3(MIND / 256, (NROW + MIND) / 256), 512, 0, stream>>>(
      Zh, Zih, NF, rnorm, cnorm,
      DK, Ai, nullptr, nullptr, nullptr, nullptr, nullptr, nullptr, nullptr);

  // blocked Gauss-Jordan inverse, 2 launches/iter (R9 proven structure)
  gj_diag<<<1, 256, 0, stream>>>(Ai, Pall, 0);
  gj_prep<<<64, 256, 0, stream>>>(Ai, Pall, CP, Bsave, 0);
  for (int k = 0; k < 32; ++k) {
    gj_apply<<<dim3(32, 32), 256, 0, stream>>>(Ai, Pall, CP, Bsave, k);
    if (k < 31) gj_prep<<<64, 256, 0, stream>>>(Ai, Pall, CP, Bsave, k + 1);
  }

  // u + Kih (one Ai pass); PASS2: Rt = fp16(ip^T Kinv) + fused colsumR
  rowsum_cast<<<MIND / 4, 256, 0, stream>>>(Ai, u, Kih);
  mfma_gemm256f<2><<<dim3(8, 6), 512, 0, stream>>>(
      ipTh, Kih, MIND, ip, nullptr,
      Rt, nullptr, nullptr, u, colsumR, nullptr, nullptr, nullptr, nullptr);

  // PASS 1: B' = [Kih;Rt] -> varacc (bn<8) + x_new (bn>=8), XCD-swizzled
  mfma_gemm256f<1><<<dim3((MIND + NF) / 256, NROW / 256), 512, 0, stream>>>(
      DK, Kih, MIND, nullptr, nullptr,
      nullptr, out, DK, u, varacc, colsumR, stdv, meanv, mask);

  var_finalize<<<NROW / 256, 256, 0, stream>>>(varacc, mask, out + (size_t)NROW * NF);
}